// Round 13
// baseline (36.276 us; speedup 1.0000x reference)
//
#include <hip/hip_runtime.h>
#include <hip/hip_bf16.h>
#include <math.h>

// Problem constants: N=4, E=64, L=512, D=768
#define PN 4
#define PE 64
#define PL 512
#define PD 768
#define PK2 (2 * PD)        // 1536
#define PM (PN * PE)        // 256 rows

#define EG 4                // entities per pool block
#define DCW 64              // d-columns per pool block (1 f32 per lane)
#define NDC (PD / DCW)      // 12 d-chunks
#define NXCD 8
#define NPW 1056            // pool+convert blocks (8 XCD x 132)
#define NMG 96              // mean-GEMM blocks (96 x 8 waves = 768 tiles)

using bf16x8 = __attribute__((ext_vector_type(8))) short;
using f32x4  = __attribute__((ext_vector_type(4))) float;

static __device__ __forceinline__ unsigned short f2bf(float x) {
    unsigned int u = __float_as_uint(x);
    unsigned int r = (u + 0x7FFFu + ((u >> 16) & 1u)) >> 16;   // RNE
    return (unsigned short)r;
}

// ---------------------------------------------------------------------------
// k1: max-pool (VALU) + mean-GEMM (MFMA) + W-convert, one kernel, all
// independent work.
//  bid <  1056: R11's XCD-aware mapping (xcd = bid&7, idx = bid>>3):
//    idx <  96 : max-only pool. Block = (n = xcd>>1, d-half = xcd&1,
//                eg = idx/6, dc = dhalf*6 + idx%6). 8 waves x 64-l window,
//                ballot SGPR masks, cand = mval*v (includes reference's 0
//                candidate for masked-out rows -> no fixup), fmax only.
//                LDS 8KB tree-reduce -> Pb max half.
//    idx >= 96 : W f32 -> Wb bf16 (XCD-local stripe).
//  bid >= 1056: mean via MFMA: tile t = (bid-1056)*8 + wave. Per tile:
//    mean[e-tile 16][d-tile 16] = sum_l mask[n,e,l]*doc[n,l,d], K=512,
//    16x mfma_16x16x32_bf16, A=mask (0/1 -> bf16 exact), B=doc (f2bf
//    in-register, strided dword gather), f32 accum -> /len -> Pb mean half.
// ---------------------------------------------------------------------------
__global__ __launch_bounds__(512) void k1_pool_mean(
    const float* __restrict__ doc,    // [N][L][D]
    const float* __restrict__ map,    // [N][E][L]
    const float* __restrict__ lens,   // [N][E]
    const float* __restrict__ W,      // [768][1536]
    unsigned short* __restrict__ Pb,  // [256][1536] bf16
    unsigned short* __restrict__ Wb)  // [768][1536] bf16
{
    const int bid  = blockIdx.x;
    const int tid  = threadIdx.x;
    const int w    = tid >> 6;
    const int lane = tid & 63;

    if (bid >= NPW) {
        // ---------------- mean-GEMM blocks ----------------
        const int t  = (bid - NPW) * 8 + w;   // 0..767
        const int ct = t % 48;
        const int rq = (t / 48) & 3;          // 16-entity quarter
        const int n  = t / 192;
        const int r0 = rq * 16;               // e-tile base
        const int d0 = ct * 16;               // d-tile base
        const int fr = lane & 15;
        const int kg = lane >> 4;

        const float* mrow = map + ((size_t)n * PE + r0 + fr) * PL + kg * 8;
        const float* dcol = doc + (size_t)n * PL * PD + d0 + fr;

        f32x4 acc = {0.f, 0.f, 0.f, 0.f};
        for (int k0 = 0; k0 < PL; k0 += 32) {
            // A-frag: mask row, 8 consecutive l (0/1 -> bf16 exact)
            const float4 ma = *reinterpret_cast<const float4*>(mrow + k0);
            const float4 mb = *reinterpret_cast<const float4*>(mrow + k0 + 4);
            union { unsigned short s[8]; bf16x8 v; } af;
            af.s[0] = (ma.x != 0.f) ? 0x3F80 : 0;
            af.s[1] = (ma.y != 0.f) ? 0x3F80 : 0;
            af.s[2] = (ma.z != 0.f) ? 0x3F80 : 0;
            af.s[3] = (ma.w != 0.f) ? 0x3F80 : 0;
            af.s[4] = (mb.x != 0.f) ? 0x3F80 : 0;
            af.s[5] = (mb.y != 0.f) ? 0x3F80 : 0;
            af.s[6] = (mb.z != 0.f) ? 0x3F80 : 0;
            af.s[7] = (mb.w != 0.f) ? 0x3F80 : 0;
            // B-frag: doc col d0+fr, 8 l-rows (strided dword gather)
            union { unsigned short s[8]; bf16x8 v; } bfr;
            #pragma unroll
            for (int j = 0; j < 8; ++j)
                bfr.s[j] = f2bf(dcol[(size_t)(k0 + kg * 8 + j) * PD]);
            acc = __builtin_amdgcn_mfma_f32_16x16x32_bf16(af.v, bfr.v, acc, 0, 0, 0);
        }
        // C layout: col = lane&15 (d), row = kg*4+j (e within tile)
        const int d = d0 + fr;
        #pragma unroll
        for (int j = 0; j < 4; ++j) {
            const int ne = n * PE + r0 + kg * 4 + j;
            Pb[(size_t)ne * PK2 + PD + d] = f2bf(acc[j] / lens[ne]);
        }
        return;
    }

    const int xcd = bid & (NXCD - 1);
    const int idx = bid >> 3;           // 0..131

    if (idx >= 96) {
        // ---------------- W conversion (XCD-local stripe) ----------------
        const int ci = xcd * 36 + (idx - 96);           // 0..287
        const size_t i = ((size_t)ci * 512 + tid) * 8;
        const float4 a = *reinterpret_cast<const float4*>(W + i);
        const float4 c = *reinterpret_cast<const float4*>(W + i + 4);
        union { unsigned short s[8]; uint4 v; } r;
        r.s[0] = f2bf(a.x); r.s[1] = f2bf(a.y); r.s[2] = f2bf(a.z); r.s[3] = f2bf(a.w);
        r.s[4] = f2bf(c.x); r.s[5] = f2bf(c.y); r.s[6] = f2bf(c.z); r.s[7] = f2bf(c.w);
        *reinterpret_cast<uint4*>(Wb + i) = r.v;
        return;
    }

    // ---------------- max-only pool ----------------
    __shared__ float lmax[8][EG][64];   // 8 KB

    const int n   = xcd >> 1;            // XCD pair owns one n
    const int dh  = xcd & 1;             // d-half
    const int eg  = idx / 6;             // 0..15
    const int dc  = dh * 6 + (idx % 6);  // 0..11
    const int e0  = eg * EG;
    const int d0  = dc * DCW;

    unsigned long long mk[EG];
    #pragma unroll
    for (int e = 0; e < EG; ++e) {
        const float m = map[((size_t)n * PE + e0 + e) * PL + w * 64 + lane];
        mk[e] = __ballot(m != 0.0f);
    }

    const float* docp = doc + ((size_t)n * PL + w * 64) * PD + d0 + lane;

    float mx[EG];
    #pragma unroll
    for (int e = 0; e < EG; ++e) mx[e] = -INFINITY;

    #pragma unroll 16
    for (int l = 0; l < 64; ++l) {
        const float v = docp[(size_t)l * PD];
        #pragma unroll
        for (int e = 0; e < EG; ++e) {
            const float mval = ((mk[e] >> l) & 1ull) ? 1.0f : 0.0f;  // s_cselect
            mx[e] = fmaxf(mx[e], mval * v);   // == reference mask*doc elem
        }
    }

    #pragma unroll
    for (int e = 0; e < EG; ++e) lmax[w][e][lane] = mx[e];
    __syncthreads();

    if (tid < 256) {                     // 256 (e,d) slots
        const int e  = tid >> 6;
        const int ln = tid & 63;
        const int ne = n * PE + e0 + e;
        float m = lmax[0][e][ln];
        #pragma unroll
        for (int ww = 1; ww < 8; ++ww) m = fmaxf(m, lmax[ww][e][ln]);
        Pb[(size_t)ne * PK2 + d0 + ln] = f2bf(m);
    }
}

// ---------------------------------------------------------------------------
// gemm_ks2x (unchanged from R11): MFMA bf16 16x16x32, K-split 2, XCD-aware
// tile mapping (XCD owns a 6-wide ct stripe; W slice L2-resident).
// ---------------------------------------------------------------------------
__global__ __launch_bounds__(128) void gemm_ks2x(
    const unsigned short* __restrict__ Pb,  // [256][1536] bf16
    const unsigned short* __restrict__ Wb,  // [768][1536] bf16
    const float* __restrict__ b,            // [768]
    float* __restrict__ out)                // [256][768]
{
    __shared__ f32x4 red[64];

    const int w    = threadIdx.x >> 6;
    const int lane = threadIdx.x & 63;
    const int bid  = blockIdx.x;
    const int xcd  = bid & (NXCD - 1);
    const int idx  = bid >> 3;               // 0..95
    const int ct = xcd * 6 + (idx >> 4);     // 0..47
    const int rt = idx & 15;                 // 0..15
    const int r0 = rt * 16, d0 = ct * 16;

    const int fr = lane & 15;
    const int kg = lane >> 4;
    const int kb = w * (PK2 / 2);            // 768-wide K slice per wave

    const unsigned short* pA = Pb + (size_t)(r0 + fr) * PK2 + kb + kg * 8;
    const unsigned short* pB = Wb + (size_t)(d0 + fr) * PK2 + kb + kg * 8;

    f32x4 acc0 = {0.f, 0.f, 0.f, 0.f};
    f32x4 acc1 = {0.f, 0.f, 0.f, 0.f};
    #pragma unroll
    for (int k0 = 0; k0 < PK2 / 2; k0 += 64) {
        const bf16x8 a0 = *reinterpret_cast<const bf16x8*>(pA + k0);
        const bf16x8 b0 = *reinterpret_cast<const bf16x8*>(pB + k0);
        acc0 = __builtin_amdgcn_mfma_f32_16x16x32_bf16(a0, b0, acc0, 0, 0, 0);
        const bf16x8 a1 = *reinterpret_cast<const bf16x8*>(pA + k0 + 32);
        const bf16x8 b1 = *reinterpret_cast<const bf16x8*>(pB + k0 + 32);
        acc1 = __builtin_amdgcn_mfma_f32_16x16x32_bf16(a1, b1, acc1, 0, 0, 0);
    }
    f32x4 acc = acc0 + acc1;

    if (w == 1) red[lane] = acc;
    __syncthreads();
    if (w == 0) {
        acc += red[lane];
        const int c = d0 + fr;
        const float bias = b[c];
        #pragma unroll
        for (int j = 0; j < 4; ++j)
            out[(size_t)(r0 + kg * 4 + j) * PD + c] = acc[j] + bias;
    }
}

// ===========================================================================
// Fallback: fully fused f32 (R1-proven) -- used only if ws is tiny.
// ===========================================================================
__global__ __launch_bounds__(256) void fused_kernel(
    const float* __restrict__ doc, const float* __restrict__ map,
    const float* __restrict__ lens, const float* __restrict__ W,
    const float* __restrict__ b, float* __restrict__ out)
{
    __shared__ float Prow[PK2];
    const int ne = blockIdx.x, n = ne >> 6, t = threadIdx.x;
    const float* docn = doc + (size_t)n * PL * PD;
    const float* mrow = map + (size_t)ne * PL;
    float mx0=-INFINITY, mx1=-INFINITY, mx2=-INFINITY, s0=0.f, s1=0.f, s2=0.f;
    bool has_zero = false;
    for (int l = 0; l < PL; ++l) {
        const float m = mrow[l];
        if (m != 0.0f) {
            const float* dr = docn + (size_t)l * PD;
            const float a = dr[t], c = dr[t+256], e = dr[t+512];
            mx0=fmaxf(mx0,a); s0+=a; mx1=fmaxf(mx1,c); s1+=c; mx2=fmaxf(mx2,e); s2+=e;
        } else has_zero = true;
    }
    if (has_zero) { mx0=fmaxf(mx0,0.f); mx1=fmaxf(mx1,0.f); mx2=fmaxf(mx2,0.f); }
    const float invlen = 1.0f / lens[ne];
    Prow[t]=mx0; Prow[t+256]=mx1; Prow[t+512]=mx2;
    Prow[PD+t]=s0*invlen; Prow[PD+t+256]=s1*invlen; Prow[PD+t+512]=s2*invlen;
    __syncthreads();
    #pragma unroll
    for (int i = 0; i < 3; ++i) {
        const int d = t + i*256;
        const float* wrow = W + (size_t)d * PK2;
        float acc = 0.f;
        for (int k = 0; k < PK2; k += 4) {
            const float4 w = *reinterpret_cast<const float4*>(&wrow[k]);
            acc += Prow[k]*w.x + Prow[k+1]*w.y + Prow[k+2]*w.z + Prow[k+3]*w.w;
        }
        out[(size_t)ne * PD + d] = acc + b[d];
    }
}

extern "C" void kernel_launch(void* const* d_in, const int* in_sizes, int n_in,
                              void* d_out, int out_size, void* d_ws, size_t ws_size,
                              hipStream_t stream) {
    const float* doc  = (const float*)d_in[0];   // (4,512,768)
    const float* map  = (const float*)d_in[1];   // (4,64,512)
    const float* lens = (const float*)d_in[2];   // (4,64)
    const float* W    = (const float*)d_in[3];   // (768,1536)
    const float* b    = (const float*)d_in[4];   // (768,)
    float* out = (float*)d_out;                  // (4,64,768)

    const size_t pb_bytes = (size_t)PM * PK2 * sizeof(unsigned short);   // 768 KiB
    const size_t wb_bytes = (size_t)PD * PK2 * sizeof(unsigned short);   // 2.25 MiB
    const size_t need     = pb_bytes + wb_bytes;                         // 3 MiB

    if (ws_size >= need) {
        unsigned short* Pb = (unsigned short*)d_ws;
        unsigned short* Wb = (unsigned short*)((char*)d_ws + pb_bytes);
        k1_pool_mean<<<dim3(NPW + NMG), dim3(512), 0, stream>>>(
            doc, map, lens, W, Pb, Wb);
        gemm_ks2x<<<dim3((PM / 16) * (PD / 16)), dim3(128), 0, stream>>>(Pb, Wb, b, out);
    } else {
        fused_kernel<<<dim3(PM), dim3(256), 0, stream>>>(doc, map, lens, W, b, out);
    }
}

// Round 14
// 32.323 us; speedup vs baseline: 1.1223x; 1.1223x over previous
//
#include <hip/hip_runtime.h>
#include <hip/hip_bf16.h>
#include <math.h>

// Problem constants: N=4, E=64, L=512, D=768
#define PN 4
#define PE 64
#define PL 512
#define PD 768
#define PK2 (2 * PD)        // 1536
#define PM (PN * PE)        // 256 rows

#define EG 4                // entities per pool block
#define DCW 64              // d-columns per pool block (1 f32 per lane)
#define NDC (PD / DCW)      // 12 d-chunks
#define NXCD 8
#define NPOOLB 768          // 8 XCD x 96 pool blocks (no convert arm anymore)

using bf16x8 = __attribute__((ext_vector_type(8))) short;
using f32x4  = __attribute__((ext_vector_type(4))) float;

static __device__ __forceinline__ unsigned short f2bf(float x) {
    unsigned int u = __float_as_uint(x);
    unsigned int r = (u + 0x7FFFu + ((u >> 16) & 1u)) >> 16;   // RNE
    return (unsigned short)r;
}

// ---------------------------------------------------------------------------
// pool_v8: R11's pool_v6 minus the W-convert arm. 768 blocks, 512 thr.
// XCD-aware mapping (xcd = bid&7): XCD x -> n = x>>1, d-half = x&1 so each
// XCD's doc working set (768 KB) is L2-resident across its 96 blocks.
// Block = (n, e-group of 4, d-chunk of 64); 8 waves x 64-l window = all L.
// Ballot SGPR masks; cand = mval*v (mval in {1,0} via s_cselect) == the
// reference's mask*doc element EXACTLY (masked-out -> 0 candidate, so max
// needs no has_zero fixup). LDS 16 KB tree-reduce -> Pb bf16 (max | mean).
// ---------------------------------------------------------------------------
__global__ __launch_bounds__(512) void pool_v8(
    const float* __restrict__ doc,    // [N][L][D]
    const float* __restrict__ map,    // [N][E][L]
    const float* __restrict__ lens,   // [N][E]
    unsigned short* __restrict__ Pb)  // [256][1536] bf16
{
    __shared__ float lmax[8][EG][64];   // 8 KB
    __shared__ float lsum[8][EG][64];   // 8 KB

    const int bid = blockIdx.x;
    const int tid = threadIdx.x;
    const int xcd = bid & (NXCD - 1);
    const int idx = bid >> 3;            // 0..95

    const int n   = xcd >> 1;            // XCD pair owns one n
    const int dh  = xcd & 1;             // d-half
    const int eg  = idx / 6;             // 0..15
    const int dc  = dh * 6 + (idx % 6);  // 0..11
    const int e0  = eg * EG;
    const int d0  = dc * DCW;
    const int w    = tid >> 6;
    const int lane = tid & 63;

    // per-wave 64-bit masks for its own l-window (wave-uniform SGPR)
    unsigned long long mk[EG];
    #pragma unroll
    for (int e = 0; e < EG; ++e) {
        const float m = map[((size_t)n * PE + e0 + e) * PL + w * 64 + lane];
        mk[e] = __ballot(m != 0.0f);
    }

    const float* docp = doc + ((size_t)n * PL + w * 64) * PD + d0 + lane;

    float mx[EG], sm[EG];
    #pragma unroll
    for (int e = 0; e < EG; ++e) { mx[e] = -INFINITY; sm[e] = 0.f; }

    #pragma unroll 16
    for (int l = 0; l < 64; ++l) {
        const float v = docp[(size_t)l * PD];
        #pragma unroll
        for (int e = 0; e < EG; ++e) {
            const float mval = ((mk[e] >> l) & 1ull) ? 1.0f : 0.0f;  // s_cselect
            const float cand = mval * v;      // == reference mask*doc elem
            sm[e] += cand;
            mx[e] = fmaxf(mx[e], cand);
        }
    }

    #pragma unroll
    for (int e = 0; e < EG; ++e) {
        lmax[w][e][lane] = mx[e];
        lsum[w][e][lane] = sm[e];
    }
    __syncthreads();

    // 256 (e,ln) slots; tid<256 -> max, tid>=256 -> mean
    const int slot = tid & 255;
    const int e  = slot >> 6;
    const int ln = slot & 63;
    const int ne = n * PE + e0 + e;
    const int d  = d0 + ln;
    if (tid < 256) {
        float m = lmax[0][e][ln];
        #pragma unroll
        for (int ww = 1; ww < 8; ++ww) m = fmaxf(m, lmax[ww][e][ln]);
        Pb[(size_t)ne * PK2 + d] = f2bf(m);
    } else {
        float s = lsum[0][e][ln];
        #pragma unroll
        for (int ww = 1; ww < 8; ++ww) s += lsum[ww][e][ln];
        Pb[(size_t)ne * PK2 + PD + d] = f2bf(s * (1.0f / lens[ne]));
    }
}

// ---------------------------------------------------------------------------
// gemm_wf32: R11's gemm_ks2x, but B-fragments come from W (f32) with
// in-register f32->bf16 conversion -- no Wb buffer, no convert pass.
// MFMA bf16 16x16x32, K-split 2 across 2 waves, XCD-aware tile mapping
// (XCD owns a 6-wide ct stripe; its W f32 slice = 590 KB, L2-resident).
// ---------------------------------------------------------------------------
__global__ __launch_bounds__(128) void gemm_wf32(
    const unsigned short* __restrict__ Pb,  // [256][1536] bf16
    const float* __restrict__ W,            // [768][1536] f32
    const float* __restrict__ b,            // [768]
    float* __restrict__ out)                // [256][768]
{
    __shared__ f32x4 red[64];

    const int w    = threadIdx.x >> 6;
    const int lane = threadIdx.x & 63;
    const int bid  = blockIdx.x;
    const int xcd  = bid & (NXCD - 1);
    const int idx  = bid >> 3;               // 0..95
    const int ct = xcd * 6 + (idx >> 4);     // 0..47
    const int rt = idx & 15;                 // 0..15
    const int r0 = rt * 16, d0 = ct * 16;

    const int fr = lane & 15;
    const int kg = lane >> 4;
    const int kb = w * (PK2 / 2);            // 768-wide K slice per wave

    const unsigned short* pA = Pb + (size_t)(r0 + fr) * PK2 + kb + kg * 8;
    const float*          pW = W  + (size_t)(d0 + fr) * PK2 + kb + kg * 8;

    f32x4 acc0 = {0.f, 0.f, 0.f, 0.f};
    f32x4 acc1 = {0.f, 0.f, 0.f, 0.f};
    #pragma unroll
    for (int k0 = 0; k0 < PK2 / 2; k0 += 64) {
        {
            const bf16x8 a0 = *reinterpret_cast<const bf16x8*>(pA + k0);
            const float4 w0 = *reinterpret_cast<const float4*>(pW + k0);
            const float4 w1 = *reinterpret_cast<const float4*>(pW + k0 + 4);
            union { unsigned short s[8]; bf16x8 v; } bf;
            bf.s[0] = f2bf(w0.x); bf.s[1] = f2bf(w0.y);
            bf.s[2] = f2bf(w0.z); bf.s[3] = f2bf(w0.w);
            bf.s[4] = f2bf(w1.x); bf.s[5] = f2bf(w1.y);
            bf.s[6] = f2bf(w1.z); bf.s[7] = f2bf(w1.w);
            acc0 = __builtin_amdgcn_mfma_f32_16x16x32_bf16(a0, bf.v, acc0, 0, 0, 0);
        }
        {
            const bf16x8 a1 = *reinterpret_cast<const bf16x8*>(pA + k0 + 32);
            const float4 w0 = *reinterpret_cast<const float4*>(pW + k0 + 32);
            const float4 w1 = *reinterpret_cast<const float4*>(pW + k0 + 36);
            union { unsigned short s[8]; bf16x8 v; } bf;
            bf.s[0] = f2bf(w0.x); bf.s[1] = f2bf(w0.y);
            bf.s[2] = f2bf(w0.z); bf.s[3] = f2bf(w0.w);
            bf.s[4] = f2bf(w1.x); bf.s[5] = f2bf(w1.y);
            bf.s[6] = f2bf(w1.z); bf.s[7] = f2bf(w1.w);
            acc1 = __builtin_amdgcn_mfma_f32_16x16x32_bf16(a1, bf.v, acc1, 0, 0, 0);
        }
    }
    f32x4 acc = acc0 + acc1;

    if (w == 1) red[lane] = acc;
    __syncthreads();
    if (w == 0) {
        acc += red[lane];
        const int c = d0 + fr;
        const float bias = b[c];
        #pragma unroll
        for (int j = 0; j < 4; ++j)
            out[(size_t)(r0 + kg * 4 + j) * PD + c] = acc[j] + bias;
    }
}

// ===========================================================================
// Fallback: fully fused f32 (R1-proven) -- used only if ws is tiny.
// ===========================================================================
__global__ __launch_bounds__(256) void fused_kernel(
    const float* __restrict__ doc, const float* __restrict__ map,
    const float* __restrict__ lens, const float* __restrict__ W,
    const float* __restrict__ b, float* __restrict__ out)
{
    __shared__ float Prow[PK2];
    const int ne = blockIdx.x, n = ne >> 6, t = threadIdx.x;
    const float* docn = doc + (size_t)n * PL * PD;
    const float* mrow = map + (size_t)ne * PL;
    float mx0=-INFINITY, mx1=-INFINITY, mx2=-INFINITY, s0=0.f, s1=0.f, s2=0.f;
    bool has_zero = false;
    for (int l = 0; l < PL; ++l) {
        const float m = mrow[l];
        if (m != 0.0f) {
            const float* dr = docn + (size_t)l * PD;
            const float a = dr[t], c = dr[t+256], e = dr[t+512];
            mx0=fmaxf(mx0,a); s0+=a; mx1=fmaxf(mx1,c); s1+=c; mx2=fmaxf(mx2,e); s2+=e;
        } else has_zero = true;
    }
    if (has_zero) { mx0=fmaxf(mx0,0.f); mx1=fmaxf(mx1,0.f); mx2=fmaxf(mx2,0.f); }
    const float invlen = 1.0f / lens[ne];
    Prow[t]=mx0; Prow[t+256]=mx1; Prow[t+512]=mx2;
    Prow[PD+t]=s0*invlen; Prow[PD+t+256]=s1*invlen; Prow[PD+t+512]=s2*invlen;
    __syncthreads();
    #pragma unroll
    for (int i = 0; i < 3; ++i) {
        const int d = t + i*256;
        const float* wrow = W + (size_t)d * PK2;
        float acc = 0.f;
        for (int k = 0; k < PK2; k += 4) {
            const float4 w = *reinterpret_cast<const float4*>(&wrow[k]);
            acc += Prow[k]*w.x + Prow[k+1]*w.y + Prow[k+2]*w.z + Prow[k+3]*w.w;
        }
        out[(size_t)ne * PD + d] = acc + b[d];
    }
}

extern "C" void kernel_launch(void* const* d_in, const int* in_sizes, int n_in,
                              void* d_out, int out_size, void* d_ws, size_t ws_size,
                              hipStream_t stream) {
    const float* doc  = (const float*)d_in[0];   // (4,512,768)
    const float* map  = (const float*)d_in[1];   // (4,64,512)
    const float* lens = (const float*)d_in[2];   // (4,64)
    const float* W    = (const float*)d_in[3];   // (768,1536)
    const float* b    = (const float*)d_in[4];   // (768,)
    float* out = (float*)d_out;                  // (4,64,768)

    const size_t pb_bytes = (size_t)PM * PK2 * sizeof(unsigned short);   // 768 KiB

    if (ws_size >= pb_bytes) {
        unsigned short* Pb = (unsigned short*)d_ws;
        pool_v8<<<dim3(NPOOLB), dim3(512), 0, stream>>>(doc, map, lens, Pb);
        gemm_wf32<<<dim3((PM / 16) * (PD / 16)), dim3(128), 0, stream>>>(Pb, W, b, out);
    } else {
        fused_kernel<<<dim3(PM), dim3(256), 0, stream>>>(doc, map, lens, W, b, out);
    }
}

// Round 15
// 28.654 us; speedup vs baseline: 1.2660x; 1.1280x over previous
//
#include <hip/hip_runtime.h>
#include <hip/hip_bf16.h>
#include <math.h>

// Problem constants: N=4, E=64, L=512, D=768
#define PN 4
#define PE 64
#define PL 512
#define PD 768
#define PK2 (2 * PD)        // 1536
#define PM (PN * PE)        // 256 rows

#define EG 4                // entities per pool block
#define DCW 64              // d-columns per pool block (1 f32 per lane)
#define NDC (PD / DCW)      // 12 d-chunks
#define NPOOLB 768          // pool blocks
#define NCVT 288            // W-convert blocks
#define NXCD 8

using bf16x8 = __attribute__((ext_vector_type(8))) short;
using f32x4  = __attribute__((ext_vector_type(4))) float;

static __device__ __forceinline__ unsigned short f2bf(float x) {
    unsigned int u = __float_as_uint(x);
    unsigned int r = (u + 0x7FFFu + ((u >> 16) & 1u)) >> 16;   // RNE
    return (unsigned short)r;
}

// ---------------------------------------------------------------------------
// pool_v9: R11's pool_v6 with ONE change -- the l-loop is restructured into
// explicit 8-deep load batches (named vv[0..7], loads clustered before use)
// to force 8 outstanding loads per wave (MLP). All prior pool variants
// compiled to VGPR 8-12 => 1 load in flight => latency-bound at 15-22%
// VALUBusy regardless of instruction mix.
// XCD-aware mapping (xcd = bid&7): XCD x -> n = x>>1, d-half = x&1; per-XCD
// doc slice 768 KB L2-resident. idx>=96 blocks convert W->bf16 (XCD stripe).
// cand = mval*v (SALU cselect) == reference mask*doc elem EXACTLY.
// ---------------------------------------------------------------------------
__global__ __launch_bounds__(512) void pool_v9(
    const float* __restrict__ doc,    // [N][L][D]
    const float* __restrict__ map,    // [N][E][L]
    const float* __restrict__ lens,   // [N][E]
    const float* __restrict__ W,      // [768][1536]
    unsigned short* __restrict__ Pb,  // [256][1536] bf16
    unsigned short* __restrict__ Wb)  // [768][1536] bf16
{
    const int bid = blockIdx.x;
    const int tid = threadIdx.x;
    const int xcd = bid & (NXCD - 1);   // target XCD under round-robin
    const int idx = bid >> 3;           // 0..131 within XCD

    if (idx >= 96) {
        // ---- W conversion: XCD-local stripe of W ----
        const int ci = xcd * 36 + (idx - 96);           // 0..287
        const size_t i = ((size_t)ci * 512 + tid) * 8;
        const float4 a = *reinterpret_cast<const float4*>(W + i);
        const float4 c = *reinterpret_cast<const float4*>(W + i + 4);
        union { unsigned short s[8]; uint4 v; } r;
        r.s[0] = f2bf(a.x); r.s[1] = f2bf(a.y); r.s[2] = f2bf(a.z); r.s[3] = f2bf(a.w);
        r.s[4] = f2bf(c.x); r.s[5] = f2bf(c.y); r.s[6] = f2bf(c.z); r.s[7] = f2bf(c.w);
        *reinterpret_cast<uint4*>(Wb + i) = r.v;
        return;
    }

    __shared__ float lmax[8][EG][64];   // 8 KB
    __shared__ float lsum[8][EG][64];   // 8 KB

    const int n   = xcd >> 1;            // XCD pair owns one n
    const int dh  = xcd & 1;             // d-half
    const int eg  = idx / 6;             // 0..15
    const int dc  = dh * 6 + (idx % 6);  // 0..11
    const int e0  = eg * EG;
    const int d0  = dc * DCW;
    const int w    = tid >> 6;
    const int lane = tid & 63;

    // per-wave 64-bit masks for its own l-window (wave-uniform SGPR)
    unsigned long long mk[EG];
    #pragma unroll
    for (int e = 0; e < EG; ++e) {
        const float m = map[((size_t)n * PE + e0 + e) * PL + w * 64 + lane];
        mk[e] = __ballot(m != 0.0f);
    }

    const float* docp = doc + ((size_t)n * PL + w * 64) * PD + d0 + lane;

    float mx[EG], sm[EG];
    #pragma unroll
    for (int e = 0; e < EG; ++e) { mx[e] = -INFINITY; sm[e] = 0.f; }

    // 8-deep explicit load batching: 8 loads issued as a cluster, then the
    // 8x12 VALU body consumes them. Forces MLP=8 per wave.
    #pragma unroll
    for (int lb = 0; lb < 64; lb += 8) {
        float vv[8];
        #pragma unroll
        for (int i = 0; i < 8; ++i)
            vv[i] = docp[(size_t)(lb + i) * PD];
        #pragma unroll
        for (int i = 0; i < 8; ++i) {
            const int l = lb + i;
            #pragma unroll
            for (int e = 0; e < EG; ++e) {
                const float mval = ((mk[e] >> l) & 1ull) ? 1.0f : 0.0f;  // s_cselect
                const float cand = mval * vv[i];   // == reference mask*doc elem
                sm[e] += cand;
                mx[e] = fmaxf(mx[e], cand);
            }
        }
    }

    #pragma unroll
    for (int e = 0; e < EG; ++e) {
        lmax[w][e][lane] = mx[e];
        lsum[w][e][lane] = sm[e];
    }
    __syncthreads();

    // 256 (e,ln) slots; tid<256 -> max, tid>=256 -> mean
    const int slot = tid & 255;
    const int e  = slot >> 6;
    const int ln = slot & 63;
    const int ne = n * PE + e0 + e;
    const int d  = d0 + ln;
    if (tid < 256) {
        float m = lmax[0][e][ln];
        #pragma unroll
        for (int ww = 1; ww < 8; ++ww) m = fmaxf(m, lmax[ww][e][ln]);
        Pb[(size_t)ne * PK2 + d] = f2bf(m);
    } else {
        float s = lsum[0][e][ln];
        #pragma unroll
        for (int ww = 1; ww < 8; ++ww) s += lsum[ww][e][ln];
        Pb[(size_t)ne * PK2 + PD + d] = f2bf(s * (1.0f / lens[ne]));
    }
}

// ---------------------------------------------------------------------------
// gemm_ks2x (unchanged from R11): MFMA bf16 16x16x32, K-split 2, XCD-aware
// tile mapping (XCD owns a 6-wide ct stripe; W slice L2-resident).
// ---------------------------------------------------------------------------
__global__ __launch_bounds__(128) void gemm_ks2x(
    const unsigned short* __restrict__ Pb,  // [256][1536] bf16
    const unsigned short* __restrict__ Wb,  // [768][1536] bf16
    const float* __restrict__ b,            // [768]
    float* __restrict__ out)                // [256][768]
{
    __shared__ f32x4 red[64];

    const int w    = threadIdx.x >> 6;
    const int lane = threadIdx.x & 63;
    const int bid  = blockIdx.x;
    const int xcd  = bid & (NXCD - 1);
    const int idx  = bid >> 3;               // 0..95
    const int ct = xcd * 6 + (idx >> 4);     // 0..47
    const int rt = idx & 15;                 // 0..15
    const int r0 = rt * 16, d0 = ct * 16;

    const int fr = lane & 15;
    const int kg = lane >> 4;
    const int kb = w * (PK2 / 2);            // 768-wide K slice per wave

    const unsigned short* pA = Pb + (size_t)(r0 + fr) * PK2 + kb + kg * 8;
    const unsigned short* pB = Wb + (size_t)(d0 + fr) * PK2 + kb + kg * 8;

    f32x4 acc0 = {0.f, 0.f, 0.f, 0.f};
    f32x4 acc1 = {0.f, 0.f, 0.f, 0.f};
    #pragma unroll
    for (int k0 = 0; k0 < PK2 / 2; k0 += 64) {
        const bf16x8 a0 = *reinterpret_cast<const bf16x8*>(pA + k0);
        const bf16x8 b0 = *reinterpret_cast<const bf16x8*>(pB + k0);
        acc0 = __builtin_amdgcn_mfma_f32_16x16x32_bf16(a0, b0, acc0, 0, 0, 0);
        const bf16x8 a1 = *reinterpret_cast<const bf16x8*>(pA + k0 + 32);
        const bf16x8 b1 = *reinterpret_cast<const bf16x8*>(pB + k0 + 32);
        acc1 = __builtin_amdgcn_mfma_f32_16x16x32_bf16(a1, b1, acc1, 0, 0, 0);
    }
    f32x4 acc = acc0 + acc1;

    if (w == 1) red[lane] = acc;
    __syncthreads();
    if (w == 0) {
        acc += red[lane];
        const int c = d0 + fr;
        const float bias = b[c];
        #pragma unroll
        for (int j = 0; j < 4; ++j)
            out[(size_t)(r0 + kg * 4 + j) * PD + c] = acc[j] + bias;
    }
}

// ===========================================================================
// Fallback: fully fused f32 (R1-proven) -- used only if ws is tiny.
// ===========================================================================
__global__ __launch_bounds__(256) void fused_kernel(
    const float* __restrict__ doc, const float* __restrict__ map,
    const float* __restrict__ lens, const float* __restrict__ W,
    const float* __restrict__ b, float* __restrict__ out)
{
    __shared__ float Prow[PK2];
    const int ne = blockIdx.x, n = ne >> 6, t = threadIdx.x;
    const float* docn = doc + (size_t)n * PL * PD;
    const float* mrow = map + (size_t)ne * PL;
    float mx0=-INFINITY, mx1=-INFINITY, mx2=-INFINITY, s0=0.f, s1=0.f, s2=0.f;
    bool has_zero = false;
    for (int l = 0; l < PL; ++l) {
        const float m = mrow[l];
        if (m != 0.0f) {
            const float* dr = docn + (size_t)l * PD;
            const float a = dr[t], c = dr[t+256], e = dr[t+512];
            mx0=fmaxf(mx0,a); s0+=a; mx1=fmaxf(mx1,c); s1+=c; mx2=fmaxf(mx2,e); s2+=e;
        } else has_zero = true;
    }
    if (has_zero) { mx0=fmaxf(mx0,0.f); mx1=fmaxf(mx1,0.f); mx2=fmaxf(mx2,0.f); }
    const float invlen = 1.0f / lens[ne];
    Prow[t]=mx0; Prow[t+256]=mx1; Prow[t+512]=mx2;
    Prow[PD+t]=s0*invlen; Prow[PD+t+256]=s1*invlen; Prow[PD+t+512]=s2*invlen;
    __syncthreads();
    #pragma unroll
    for (int i = 0; i < 3; ++i) {
        const int d = t + i*256;
        const float* wrow = W + (size_t)d * PK2;
        float acc = 0.f;
        for (int k = 0; k < PK2; k += 4) {
            const float4 w = *reinterpret_cast<const float4*>(&wrow[k]);
            acc += Prow[k]*w.x + Prow[k+1]*w.y + Prow[k+2]*w.z + Prow[k+3]*w.w;
        }
        out[(size_t)ne * PD + d] = acc + b[d];
    }
}

extern "C" void kernel_launch(void* const* d_in, const int* in_sizes, int n_in,
                              void* d_out, int out_size, void* d_ws, size_t ws_size,
                              hipStream_t stream) {
    const float* doc  = (const float*)d_in[0];   // (4,512,768)
    const float* map  = (const float*)d_in[1];   // (4,64,512)
    const float* lens = (const float*)d_in[2];   // (4,64)
    const float* W    = (const float*)d_in[3];   // (768,1536)
    const float* b    = (const float*)d_in[4];   // (768,)
    float* out = (float*)d_out;                  // (4,64,768)

    const size_t pb_bytes = (size_t)PM * PK2 * sizeof(unsigned short);   // 768 KiB
    const size_t wb_bytes = (size_t)PD * PK2 * sizeof(unsigned short);   // 2.25 MiB
    const size_t need     = pb_bytes + wb_bytes;                         // 3 MiB

    if (ws_size >= need) {
        unsigned short* Pb = (unsigned short*)d_ws;
        unsigned short* Wb = (unsigned short*)((char*)d_ws + pb_bytes);
        pool_v9<<<dim3(NPOOLB + NCVT), dim3(512), 0, stream>>>(
            doc, map, lens, W, Pb, Wb);
        gemm_ks2x<<<dim3((PM / 16) * (PD / 16)), dim3(128), 0, stream>>>(Pb, Wb, b, out);
    } else {
        fused_kernel<<<dim3(PM), dim3(256), 0, stream>>>(doc, map, lens, W, b, out);
    }
}

// Round 16
// 26.581 us; speedup vs baseline: 1.3647x; 1.0780x over previous
//
#include <hip/hip_runtime.h>
#include <hip/hip_bf16.h>
#include <math.h>

// Problem constants: N=4, E=64, L=512, D=768
#define PN 4
#define PE 64
#define PL 512
#define PD 768
#define PK2 (2 * PD)        // 1536
#define PM (PN * PE)        // 256 rows

#define EG 4                // entities per pool block
#define DCW 256             // d-columns per pool block (float4 per lane)
#define NPOOLB 192          // 8 XCD x 24
#define NCVT2 144           // W-convert blocks (144*1024*8 = PD*PK2)
#define NXCD 8

using bf16x8 = __attribute__((ext_vector_type(8))) short;
using f32x4  = __attribute__((ext_vector_type(4))) float;

static __device__ __forceinline__ unsigned short f2bf(float x) {
    unsigned int u = __float_as_uint(x);
    unsigned int r = (u + 0x7FFFu + ((u >> 16) & 1u)) >> 16;   // RNE
    return (unsigned short)r;
}

// ---------------------------------------------------------------------------
// pool_v10: WIDE loads. 192 pool blocks + 144 W-convert, 1024 threads.
// Pool block = (n, e-group of 4, d-chunk of 256). 16 waves; wave w owns
// l in [w*32, w*32+32). Lane owns FOUR d columns (one float4 load / iter:
// 16 B/lane = 1 KB/wave-instruction vs 256 B before -- 4x fewer VMEM
// instructions at identical traffic/VALU; latency product unchanged).
// Masks: 32-bit ballot per (wave, e) -> SGPR. cand = mval * v (s_cselect
// mval in {1,0}) == reference mask*doc elem EXACTLY (masked-out -> 0
// candidate, so max needs no fixup).
// Merge: one 64 KB LDS buffer, two phases (max, then sum) -> Pb bf16.
// XCD mapping: xcd = bid&7 -> n = xcd>>1, eg-half = xcd&1 (doc slice
// 1.6 MB L2-resident per XCD).
// ---------------------------------------------------------------------------
__global__ __launch_bounds__(1024) void pool_v10(
    const float* __restrict__ doc,    // [N][L][D]
    const float* __restrict__ map,    // [N][E][L]
    const float* __restrict__ lens,   // [N][E]
    const float* __restrict__ W,      // [768][1536]
    unsigned short* __restrict__ Pb,  // [256][1536] bf16
    unsigned short* __restrict__ Wb)  // [768][1536] bf16
{
    const int bid = blockIdx.x;
    const int tid = threadIdx.x;

    if (bid >= NPOOLB) {
        // ---- W conversion blocks ----
        const size_t i = ((size_t)(bid - NPOOLB) * 1024 + tid) * 8;
        const float4 a = *reinterpret_cast<const float4*>(W + i);
        const float4 c = *reinterpret_cast<const float4*>(W + i + 4);
        union { unsigned short s[8]; uint4 v; } r;
        r.s[0] = f2bf(a.x); r.s[1] = f2bf(a.y); r.s[2] = f2bf(a.z); r.s[3] = f2bf(a.w);
        r.s[4] = f2bf(c.x); r.s[5] = f2bf(c.y); r.s[6] = f2bf(c.z); r.s[7] = f2bf(c.w);
        *reinterpret_cast<uint4*>(Wb + i) = r.v;
        return;
    }

    __shared__ float lbuf[16][EG][DCW];   // 64 KB, reused max then sum

    const int xcd = bid & (NXCD - 1);
    const int idx = bid >> 3;            // 0..23
    const int n   = xcd >> 1;            // XCD pair owns one n
    const int eg  = (xcd & 1) * 8 + idx / 3;   // 0..15
    const int dc  = idx % 3;             // 0..2
    const int e0  = eg * EG;
    const int d0  = dc * DCW;
    const int w    = tid >> 6;           // 0..15
    const int lane = tid & 63;

    // per-wave 32-bit masks for its 32-l window (wave-uniform SGPR)
    unsigned int mk[EG];
    #pragma unroll
    for (int e = 0; e < EG; ++e) {
        const float m = map[((size_t)n * PE + e0 + e) * PL + w * 32 + (lane & 31)];
        mk[e] = (unsigned int)__ballot(m != 0.0f);
    }

    const float* docp = doc + ((size_t)n * PL + w * 32) * PD + d0 + lane * 4;

    float4 mx[EG], sm[EG];
    #pragma unroll
    for (int e = 0; e < EG; ++e) {
        mx[e] = make_float4(-INFINITY, -INFINITY, -INFINITY, -INFINITY);
        sm[e] = make_float4(0.f, 0.f, 0.f, 0.f);
    }

    #pragma unroll 8
    for (int l = 0; l < 32; ++l) {
        const float4 v = *reinterpret_cast<const float4*>(docp + (size_t)l * PD);
        #pragma unroll
        for (int e = 0; e < EG; ++e) {
            const float mval = ((mk[e] >> l) & 1u) ? 1.0f : 0.0f;  // s_cselect
            const float cx = mval * v.x, cy = mval * v.y;          // == ref elem
            const float cz = mval * v.z, cw = mval * v.w;
            sm[e].x += cx; sm[e].y += cy; sm[e].z += cz; sm[e].w += cw;
            mx[e].x = fmaxf(mx[e].x, cx); mx[e].y = fmaxf(mx[e].y, cy);
            mx[e].z = fmaxf(mx[e].z, cz); mx[e].w = fmaxf(mx[e].w, cw);
        }
    }

    // ---- phase 1: max ----
    #pragma unroll
    for (int e = 0; e < EG; ++e)
        *reinterpret_cast<float4*>(&lbuf[w][e][lane * 4]) = mx[e];
    __syncthreads();
    {
        const int e = tid >> 8;          // 0..3
        const int d = tid & 255;         // 0..255
        float m = lbuf[0][e][d];
        #pragma unroll
        for (int ww = 1; ww < 16; ++ww) m = fmaxf(m, lbuf[ww][e][d]);
        const int ne = n * PE + e0 + e;
        Pb[(size_t)ne * PK2 + d0 + d] = f2bf(m);
    }
    __syncthreads();

    // ---- phase 2: sum / mean ----
    #pragma unroll
    for (int e = 0; e < EG; ++e)
        *reinterpret_cast<float4*>(&lbuf[w][e][lane * 4]) = sm[e];
    __syncthreads();
    {
        const int e = tid >> 8;
        const int d = tid & 255;
        float s = lbuf[0][e][d];
        #pragma unroll
        for (int ww = 1; ww < 16; ++ww) s += lbuf[ww][e][d];
        const int ne = n * PE + e0 + e;
        Pb[(size_t)ne * PK2 + PD + d0 + d] = f2bf(s * (1.0f / lens[ne]));
    }
}

// ---------------------------------------------------------------------------
// gemm_ks2x (unchanged from R11): MFMA bf16 16x16x32, K-split 2, XCD-aware
// tile mapping (XCD owns a 6-wide ct stripe; W slice L2-resident).
// ---------------------------------------------------------------------------
__global__ __launch_bounds__(128) void gemm_ks2x(
    const unsigned short* __restrict__ Pb,  // [256][1536] bf16
    const unsigned short* __restrict__ Wb,  // [768][1536] bf16
    const float* __restrict__ b,            // [768]
    float* __restrict__ out)                // [256][768]
{
    __shared__ f32x4 red[64];

    const int w    = threadIdx.x >> 6;
    const int lane = threadIdx.x & 63;
    const int bid  = blockIdx.x;
    const int xcd  = bid & (NXCD - 1);
    const int idx  = bid >> 3;               // 0..95
    const int ct = xcd * 6 + (idx >> 4);     // 0..47
    const int rt = idx & 15;                 // 0..15
    const int r0 = rt * 16, d0 = ct * 16;

    const int fr = lane & 15;
    const int kg = lane >> 4;
    const int kb = w * (PK2 / 2);            // 768-wide K slice per wave

    const unsigned short* pA = Pb + (size_t)(r0 + fr) * PK2 + kb + kg * 8;
    const unsigned short* pB = Wb + (size_t)(d0 + fr) * PK2 + kb + kg * 8;

    f32x4 acc0 = {0.f, 0.f, 0.f, 0.f};
    f32x4 acc1 = {0.f, 0.f, 0.f, 0.f};
    #pragma unroll
    for (int k0 = 0; k0 < PK2 / 2; k0 += 64) {
        const bf16x8 a0 = *reinterpret_cast<const bf16x8*>(pA + k0);
        const bf16x8 b0 = *reinterpret_cast<const bf16x8*>(pB + k0);
        acc0 = __builtin_amdgcn_mfma_f32_16x16x32_bf16(a0, b0, acc0, 0, 0, 0);
        const bf16x8 a1 = *reinterpret_cast<const bf16x8*>(pA + k0 + 32);
        const bf16x8 b1 = *reinterpret_cast<const bf16x8*>(pB + k0 + 32);
        acc1 = __builtin_amdgcn_mfma_f32_16x16x32_bf16(a1, b1, acc1, 0, 0, 0);
    }
    f32x4 acc = acc0 + acc1;

    if (w == 1) red[lane] = acc;
    __syncthreads();
    if (w == 0) {
        acc += red[lane];
        const int c = d0 + fr;
        const float bias = b[c];
        #pragma unroll
        for (int j = 0; j < 4; ++j)
            out[(size_t)(r0 + kg * 4 + j) * PD + c] = acc[j] + bias;
    }
}

// ===========================================================================
// Fallback: fully fused f32 (R1-proven) -- used only if ws is tiny.
// ===========================================================================
__global__ __launch_bounds__(256) void fused_kernel(
    const float* __restrict__ doc, const float* __restrict__ map,
    const float* __restrict__ lens, const float* __restrict__ W,
    const float* __restrict__ b, float* __restrict__ out)
{
    __shared__ float Prow[PK2];
    const int ne = blockIdx.x, n = ne >> 6, t = threadIdx.x;
    const float* docn = doc + (size_t)n * PL * PD;
    const float* mrow = map + (size_t)ne * PL;
    float mx0=-INFINITY, mx1=-INFINITY, mx2=-INFINITY, s0=0.f, s1=0.f, s2=0.f;
    bool has_zero = false;
    for (int l = 0; l < PL; ++l) {
        const float m = mrow[l];
        if (m != 0.0f) {
            const float* dr = docn + (size_t)l * PD;
            const float a = dr[t], c = dr[t+256], e = dr[t+512];
            mx0=fmaxf(mx0,a); s0+=a; mx1=fmaxf(mx1,c); s1+=c; mx2=fmaxf(mx2,e); s2+=e;
        } else has_zero = true;
    }
    if (has_zero) { mx0=fmaxf(mx0,0.f); mx1=fmaxf(mx1,0.f); mx2=fmaxf(mx2,0.f); }
    const float invlen = 1.0f / lens[ne];
    Prow[t]=mx0; Prow[t+256]=mx1; Prow[t+512]=mx2;
    Prow[PD+t]=s0*invlen; Prow[PD+t+256]=s1*invlen; Prow[PD+t+512]=s2*invlen;
    __syncthreads();
    #pragma unroll
    for (int i = 0; i < 3; ++i) {
        const int d = t + i*256;
        const float* wrow = W + (size_t)d * PK2;
        float acc = 0.f;
        for (int k = 0; k < PK2; k += 4) {
            const float4 w = *reinterpret_cast<const float4*>(&wrow[k]);
            acc += Prow[k]*w.x + Prow[k+1]*w.y + Prow[k+2]*w.z + Prow[k+3]*w.w;
        }
        out[(size_t)ne * PD + d] = acc + b[d];
    }
}

extern "C" void kernel_launch(void* const* d_in, const int* in_sizes, int n_in,
                              void* d_out, int out_size, void* d_ws, size_t ws_size,
                              hipStream_t stream) {
    const float* doc  = (const float*)d_in[0];   // (4,512,768)
    const float* map  = (const float*)d_in[1];   // (4,64,512)
    const float* lens = (const float*)d_in[2];   // (4,64)
    const float* W    = (const float*)d_in[3];   // (768,1536)
    const float* b    = (const float*)d_in[4];   // (768,)
    float* out = (float*)d_out;                  // (4,64,768)

    const size_t pb_bytes = (size_t)PM * PK2 * sizeof(unsigned short);   // 768 KiB
    const size_t wb_bytes = (size_t)PD * PK2 * sizeof(unsigned short);   // 2.25 MiB
    const size_t need     = pb_bytes + wb_bytes;                         // 3 MiB

    if (ws_size >= need) {
        unsigned short* Pb = (unsigned short*)d_ws;
        unsigned short* Wb = (unsigned short*)((char*)d_ws + pb_bytes);
        pool_v10<<<dim3(NPOOLB + NCVT2), dim3(1024), 0, stream>>>(
            doc, map, lens, W, Pb, Wb);
        gemm_ks2x<<<dim3((PM / 16) * (PD / 16)), dim3(128), 0, stream>>>(Pb, Wb, b, out);
    } else {
        fused_kernel<<<dim3(PM), dim3(256), 0, stream>>>(doc, map, lens, W, b, out);
    }
}